// Round 13
// baseline (50.863 us; speedup 1.0000x reference)
//
#include <hip/hip_runtime.h>

#define NT 24
#define SQ 1024
#define NB 1024
#define NSEG 64
#define LSEG 16
#define CH 4

typedef float f32x16 __attribute__((ext_vector_type(16)));
typedef short bf16x8 __attribute__((ext_vector_type(8)));
typedef unsigned int uint2v __attribute__((ext_vector_type(2)));

__device__ __forceinline__ unsigned short bfrnd(float x) {
    unsigned u = __float_as_uint(x);
    return (unsigned short)((u + 0x7fffu + ((u >> 16) & 1u)) >> 16);
}
__device__ __forceinline__ unsigned cvtpk(float lo, float hi) {
    unsigned r;
    asm("v_cvt_pk_bf16_f32 %0, %1, %2" : "=v"(r) : "v"(lo), "v"(hi));
    return r;
}

// Tag/mask bundle for one 4-step chunk (loaded TWO chunks ahead so the
// dependent em-gather has its tag resident when issued one chunk ahead).
struct PT { int4 msk; int tg0, tg1, tgp; };

__device__ __forceinline__ void pt_load(PT& pt, const int* __restrict__ tbl,
                                        const int* __restrict__ mbl, int t0, int hi)
{
    pt.msk = *(const int4*)(mbl + t0);
    int t = t0 + 2 * hi;                       // (t0 even) -> 8B aligned
    int2 tt = *(const int2*)(tbl + t);
    pt.tg0 = tt.x & 31;
    pt.tg1 = tt.y & 31;
    pt.tgp = tbl[t > 0 ? t - 1 : 0] & 31;
}

// em chunk: 3 float4 per step per lane (lane c = batch, hi = tag-quad half).
__device__ __forceinline__ void ldem(float (&e)[CH][12],
                                     const float* __restrict__ fbl, int t0, int hi)
{
#pragma unroll
    for (int k = 0; k < CH; ++k) {
        const float* r = fbl + (size_t)(t0 + k) * NT + hi * 4;
        float4 e0 = *(const float4*)(r);
        float4 e1 = *(const float4*)(r + 8);
        float4 e2 = *(const float4*)(r + 16);
        e[k][0] = e0.x; e[k][1] = e0.y; e[k][2] = e0.z; e[k][3] = e0.w;
        e[k][4] = e1.x; e[k][5] = e1.y; e[k][6] = e1.z; e[k][7] = e1.w;
        e[k][8] = e2.x; e[k][9] = e2.y; e[k][10] = e2.z; e[k][11] = e2.w;
    }
}

// MODE: 0 normal, 1 first chunk of sequence (t=0 init), 3 warmup (no numerator).
// RN: renormalize at chunk end (every other chunk -> every 8 steps).
template<int MODE, bool RN>
__device__ __forceinline__ void run_chunk(
    const float (&em)[CH][12], const PT& pt, float gem0, float gem1,
    bf16x8 A1, bf16x8 A2,
    const float* __restrict__ ldsT, const float* __restrict__ ldsS,
    int hi, float (&w)[12], float& lz2, float& numAcc, int& cnt)
{
    // ---- numerator: lane (hi,c) owns steps t0+2hi+{0,1} of batch c ----
    if (MODE != 3) {
        int m0 = hi ? pt.msk.z : pt.msk.x;
        int m1 = hi ? pt.msk.w : pt.msk.y;
        float c0;
        if (MODE == 1 && hi == 0)
            c0 = ldsS[pt.tg0] + gem0;              // t=0: start+em0, unmasked
        else
            c0 = m0 ? (ldsT[pt.tgp * NT + pt.tg0] + gem0) : 0.0f;
        float c1 = m1 ? (ldsT[pt.tg0 * NT + pt.tg1] + gem1) : 0.0f;
        numAcc += c0 + c1;
        if (hi == 0)
            cnt += (pt.msk.x ? 1 : 0) + (pt.msk.y ? 1 : 0) +
                   (pt.msk.z ? 1 : 0) + (pt.msk.w ? 1 : 0);
    }
    // ---- w recurrence: 4 steps, all in registers ----
#pragma unroll
    for (int k = 0; k < CH; ++k) {
        int mkk = (k == 0) ? pt.msk.x : (k == 1) ? pt.msk.y
                : (k == 2) ? pt.msk.z : pt.msk.w;
        if (MODE == 1 && k == 0) {
#pragma unroll
            for (int r = 0; r < 12; ++r) {
                int R = (r & 3) + 8 * (r >> 2);
                w[r] = __expf(ldsS[R + 4 * hi] + em[0][r]);
            }
            continue;
        }
        // B = bf16(W) in MFMA-B layout via cvt_pk + permlane32_swap (verified R5)
        unsigned aw = cvtpk(w[0], w[1]);
        unsigned bw = cvtpk(w[2], w[3]);
        unsigned cw = cvtpk(w[4], w[5]);
        unsigned dw = cvtpk(w[6], w[7]);
        unsigned ew = cvtpk(w[8], w[9]);
        unsigned fw = cvtpk(w[10], w[11]);
        uint2v s1 = __builtin_amdgcn_permlane32_swap(aw, cw, false, false);
        uint2v s2 = __builtin_amdgcn_permlane32_swap(bw, dw, false, false);
        uint2v s3 = __builtin_amdgcn_permlane32_swap(ew, 0u, false, false);
        uint2v s4 = __builtin_amdgcn_permlane32_swap(fw, 0u, false, false);
        union { unsigned u[4]; bf16x8 v; } B1, B2;
        B1.u[0] = s1[0]; B1.u[1] = s2[0]; B1.u[2] = s1[1]; B1.u[3] = s2[1];
        B2.u[0] = s3[0]; B2.u[1] = s4[0]; B2.u[2] = s3[1]; B2.u[3] = s4[1];
        // independent MFMAs (no serial acc dependency)
        f32x16 z16 = {};
        f32x16 acc1 = __builtin_amdgcn_mfma_f32_32x32x16_bf16(A1, B1.v, z16, 0, 0, 0);
        f32x16 acc2 = __builtin_amdgcn_mfma_f32_32x32x16_bf16(A2, B2.v, z16, 0, 0, 0);
        bool m = (mkk != 0);
#pragma unroll
        for (int r = 0; r < 12; ++r) {
            float q = (acc1[r] + acc2[r]) * __expf(em[k][r]);
            w[r] = m ? q : w[r];
        }
        if (RN && k == CH - 1) {   // every 8 steps; invariant stays exact
            float zh = ((w[0] + w[1]) + (w[2] + w[3])) +
                       ((w[4] + w[5]) + (w[6] + w[7])) +
                       ((w[8] + w[9]) + (w[10] + w[11]));
            float zt = zh + __shfl_xor(zh, 32);
            float rz = __builtin_amdgcn_rcpf(zt);
            lz2 += __log2f(zt);
#pragma unroll
            for (int r = 0; r < 12; ++r) w[r] *= rz;
        }
    }
}

// One pipeline iteration, all indices compile-time (rule #20).
// NC chunks total; WARM2: first two chunks are warmup (p>0).
template<int I, int NC, bool WARM2>
__device__ __forceinline__ void iter_fn(
    int a, const float* __restrict__ fbl, const int* __restrict__ tbl,
    const int* __restrict__ mbl,
    float (&em)[2][CH][12], PT (&pt)[3], float (&gem)[2][2],
    bf16x8 A1, bf16x8 A2,
    const float* __restrict__ ldsT, const float* __restrict__ ldsS,
    int hi, float (&w)[12], float& lz2, float& numAcc, int& cnt)
{
    const int t0 = a + 4 * I - (WARM2 ? 8 : 0);
    if (I + 2 < NC) pt_load(pt[(I + 2) % 3], tbl, mbl, t0 + 8, hi);
    if (I + 1 < NC) ldem(em[(I + 1) & 1], fbl, t0 + 4, hi);
    constexpr int FM = WARM2 ? 2 : 0;
    if (I + 1 < NC && I + 1 >= FM) {
        const PT& pn = pt[(I + 1) % 3];
        gem[(I + 1) & 1][0] = fbl[(size_t)(t0 + 4 + 2 * hi) * NT + pn.tg0];
        gem[(I + 1) & 1][1] = fbl[(size_t)(t0 + 5 + 2 * hi) * NT + pn.tg1];
    }
    constexpr int MODE = (WARM2 && I < 2) ? 3 : ((!WARM2 && I == 0) ? 1 : 0);
    run_chunk<MODE, (I & 1) != 0>(em[I & 1], pt[I % 3], gem[I & 1][0], gem[I & 1][1],
                                  A1, A2, ldsT, ldsS, hi, w, lz2, numAcc, cnt);
}

extern "C" __global__ void __launch_bounds__(64)
crf_fwd(const float* __restrict__ feat,
        const int* __restrict__ maskp, const int* __restrict__ target,
        const float* __restrict__ startT, const float* __restrict__ endT,
        const float* __restrict__ trans,
        float* __restrict__ dP, float* __restrict__ nP, int* __restrict__ cP)
{
    __shared__ float ldsT[NT * NT];
    __shared__ float ldsS[NT];
    __shared__ float ldsE[NT];

    const int tid = threadIdx.x;
    const int hi = tid >> 5;
    const int c = tid & 31;
    const int bid = blockIdx.x;       // 2048 = (bg, p)
    const int bg = bid >> 6;          // 0..31
    const int p = bid & (NSEG - 1);   // 0..63
    const int b = bg * 32 + c;

    for (int i = tid; i < NT * NT; i += 64) ldsT[i] = trans[i];
    if (tid < NT) { ldsS[tid] = startT[tid]; ldsE[tid] = endT[tid]; }
    __syncthreads();

    // A = exp(trans^T) constant frags: A[row=c][k] = exp(trans[k][c]), pad 0
    union { unsigned short s[8]; bf16x8 v; } A1u, A2u;
#pragma unroll
    for (int j = 0; j < 8; ++j) {
        int k1 = 8 * hi + j;
        float v1 = (c < NT && k1 < NT) ? __expf(ldsT[k1 * NT + c]) : 0.0f;
        A1u.s[j] = bfrnd(v1);
        int k2 = 16 + 8 * hi + j;
        float v2 = (c < NT && k2 < NT) ? __expf(ldsT[k2 * NT + c]) : 0.0f;
        A2u.s[j] = bfrnd(v2);
    }

    const float* fbl = feat + (size_t)b * SQ * NT;
    const int* tbl = target + (size_t)b * SQ;
    const int* mbl = maskp + (size_t)b * SQ;

    float w[12];
#pragma unroll
    for (int r = 0; r < 12; ++r) w[r] = 1.0f;
    float lz2 = 0.f, sub2 = 0.f, numAcc = 0.f;
    int cnt = 0;
    const int a = p * LSEG;

    float em[2][CH][12];
    PT pt[3];
    float gem[2][2];

    if (p > 0) {
        // prologue: tags 2-ahead, em 1-ahead; 8-step warmup (2 chunks)
        pt_load(pt[0], tbl, mbl, a - 8, hi);
        pt_load(pt[1], tbl, mbl, a - 4, hi);
        ldem(em[0], fbl, a - 8, hi);
        iter_fn<0, 6, true>(a, fbl, tbl, mbl, em, pt, gem, A1u.v, A2u.v, ldsT, ldsS, hi, w, lz2, numAcc, cnt);
        iter_fn<1, 6, true>(a, fbl, tbl, mbl, em, pt, gem, A1u.v, A2u.v, ldsT, ldsS, hi, w, lz2, numAcc, cnt);
        // capture segment-start scale (state = w_{a-1}); cancels warmup init
        {
            float zh = ((w[0] + w[1]) + (w[2] + w[3])) + ((w[4] + w[5]) + (w[6] + w[7])) +
                       ((w[8] + w[9]) + (w[10] + w[11]));
            float zt = zh + __shfl_xor(zh, 32);
            sub2 = lz2 + __log2f(zt);
        }
        iter_fn<2, 6, true>(a, fbl, tbl, mbl, em, pt, gem, A1u.v, A2u.v, ldsT, ldsS, hi, w, lz2, numAcc, cnt);
        iter_fn<3, 6, true>(a, fbl, tbl, mbl, em, pt, gem, A1u.v, A2u.v, ldsT, ldsS, hi, w, lz2, numAcc, cnt);
        iter_fn<4, 6, true>(a, fbl, tbl, mbl, em, pt, gem, A1u.v, A2u.v, ldsT, ldsS, hi, w, lz2, numAcc, cnt);
        iter_fn<5, 6, true>(a, fbl, tbl, mbl, em, pt, gem, A1u.v, A2u.v, ldsT, ldsS, hi, w, lz2, numAcc, cnt);
    } else {
        pt_load(pt[0], tbl, mbl, 0, hi);
        pt_load(pt[1], tbl, mbl, 4, hi);
        ldem(em[0], fbl, 0, hi);
        gem[0][0] = fbl[(size_t)(2 * hi) * NT + pt[0].tg0];
        gem[0][1] = fbl[(size_t)(2 * hi + 1) * NT + pt[0].tg1];
        iter_fn<0, 4, false>(0, fbl, tbl, mbl, em, pt, gem, A1u.v, A2u.v, ldsT, ldsS, hi, w, lz2, numAcc, cnt);
        iter_fn<1, 4, false>(0, fbl, tbl, mbl, em, pt, gem, A1u.v, A2u.v, ldsT, ldsS, hi, w, lz2, numAcc, cnt);
        iter_fn<2, 4, false>(0, fbl, tbl, mbl, em, pt, gem, A1u.v, A2u.v, ldsT, ldsS, hi, w, lz2, numAcc, cnt);
        iter_fn<3, 4, false>(0, fbl, tbl, mbl, em, pt, gem, A1u.v, A2u.v, ldsT, ldsS, hi, w, lz2, numAcc, cnt);
    }

    // ---- segment epilogue ----
    float ze = 0.0f;
#pragma unroll
    for (int r = 0; r < 12; ++r) {
        int R = (r & 3) + 8 * (r >> 2) + 4 * hi;
        float wv = w[r];
        if (p == NSEG - 1) wv *= __expf(ldsE[R]);
        ze += wv;
    }
    float zt = ze + __shfl_xor(ze, 32);
    float res = (lz2 + __log2f(zt) - sub2) * 0.6931471805599453f;
    float ntot = numAcc + __shfl_xor(numAcc, 32);
    if (hi == 0) {
        dP[p * NB + b] = res;
        nP[p * NB + b] = ntot;
        cP[p * NB + b] = cnt;
    }
}

extern "C" __global__ void __launch_bounds__(64)
crf_combine(const float* __restrict__ dP, const float* __restrict__ nP,
            const int* __restrict__ cP, const int* __restrict__ target,
            const float* __restrict__ endT, float* __restrict__ bpart)
{
    const int b = blockIdx.x * 64 + threadIdx.x;
    float den = 0.f, num = 0.f;
    int cnt = 0;
#pragma unroll 8
    for (int p = 0; p < NSEG; ++p) {
        den += dP[p * NB + b];
        num += nP[p * NB + b];
        cnt += cP[p * NB + b];
    }
    int lastTag = target[(size_t)b * SQ + (cnt - 1)];
    float llh = (num + endT[lastTag]) - den;
#pragma unroll
    for (int m = 1; m < 64; m <<= 1) llh += __shfl_xor(llh, m, 64);
    if (threadIdx.x == 0) bpart[blockIdx.x] = llh;
}

extern "C" __global__ void __launch_bounds__(64)
crf_final(const float* __restrict__ bpart, float* __restrict__ out)
{
    float s = (threadIdx.x < NB / 64) ? bpart[threadIdx.x] : 0.0f;
#pragma unroll
    for (int m = 1; m < 64; m <<= 1) s += __shfl_xor(s, m, 64);
    if (threadIdx.x == 0) out[0] = -s * (1.0f / NB);
}

extern "C" void kernel_launch(void* const* d_in, const int* in_sizes, int n_in,
                              void* d_out, int out_size, void* d_ws, size_t ws_size,
                              hipStream_t stream)
{
    const float* feat   = (const float*)d_in[0];
    const int*   maskp  = (const int*)d_in[1];
    const int*   target = (const int*)d_in[2];
    const float* startT = (const float*)d_in[3];
    const float* endT   = (const float*)d_in[4];
    const float* trans  = (const float*)d_in[5];

    float* dP = (float*)d_ws;                    // [NSEG*NB]
    float* nP = dP + NSEG * NB;                  // [NSEG*NB]
    int*   cP = (int*)(nP + NSEG * NB);          // [NSEG*NB]
    float* bpart = (float*)(cP + NSEG * NB);     // [NB/64]

    crf_fwd<<<(NB / 32) * NSEG, 64, 0, stream>>>(feat, maskp, target, startT, endT,
                                                 trans, dP, nP, cP);
    crf_combine<<<NB / 64, 64, 0, stream>>>(dP, nP, cP, target, endT, bpart);
    crf_final<<<1, 64, 0, stream>>>(bpart, (float*)d_out);
}

// Round 14
// 41.933 us; speedup vs baseline: 1.2130x; 1.2130x over previous
//
#include <hip/hip_runtime.h>

#define NT 24
#define SQ 1024
#define NB 1024
#define NSEG 32
#define LSEG 32
#define CH 4

typedef float f32x16 __attribute__((ext_vector_type(16)));
typedef short bf16x8 __attribute__((ext_vector_type(8)));
typedef unsigned int uint2v __attribute__((ext_vector_type(2)));

__device__ __forceinline__ unsigned short bfrnd(float x) {
    unsigned u = __float_as_uint(x);
    return (unsigned short)((u + 0x7fffu + ((u >> 16) & 1u)) >> 16);
}
__device__ __forceinline__ unsigned cvtpk(float lo, float hi) {
    unsigned r;
    asm("v_cvt_pk_bf16_f32 %0, %1, %2" : "=v"(r) : "v"(lo), "v"(hi));
    return r;
}

// Tag/mask bundle for one 4-step chunk (loaded TWO chunks ahead so the
// dependent em-gather has its tag resident when issued one chunk ahead).
struct PT { int4 msk; int tg0, tg1, tgp; };

__device__ __forceinline__ void pt_load(PT& pt, const int* __restrict__ tbl,
                                        const int* __restrict__ mbl, int t0, int hi)
{
    pt.msk = *(const int4*)(mbl + t0);
    int t = t0 + 2 * hi;                       // (t0 even) -> 8B aligned
    int2 tt = *(const int2*)(tbl + t);
    pt.tg0 = tt.x & 31;
    pt.tg1 = tt.y & 31;
    pt.tgp = tbl[t > 0 ? t - 1 : 0] & 31;
}

// em chunk: 3 float4 per step per lane (lane c = batch, hi = tag-quad half).
__device__ __forceinline__ void ldem(float (&e)[CH][12],
                                     const float* __restrict__ fbl, int t0, int hi)
{
#pragma unroll
    for (int k = 0; k < CH; ++k) {
        const float* r = fbl + (size_t)(t0 + k) * NT + hi * 4;
        float4 e0 = *(const float4*)(r);
        float4 e1 = *(const float4*)(r + 8);
        float4 e2 = *(const float4*)(r + 16);
        e[k][0] = e0.x; e[k][1] = e0.y; e[k][2] = e0.z; e[k][3] = e0.w;
        e[k][4] = e1.x; e[k][5] = e1.y; e[k][6] = e1.z; e[k][7] = e1.w;
        e[k][8] = e2.x; e[k][9] = e2.y; e[k][10] = e2.z; e[k][11] = e2.w;
    }
}

// MODE: 0 normal, 1 first chunk of sequence (t=0 init), 3 warmup (no numerator).
// RN: renormalize at chunk end (every other chunk -> every 8 steps).
template<int MODE, bool RN>
__device__ __forceinline__ void run_chunk(
    const float (&em)[CH][12], const PT& pt, float gem0, float gem1,
    bf16x8 A1, bf16x8 A2,
    const float* __restrict__ ldsT, const float* __restrict__ ldsS,
    int hi, float (&w)[12], float& lz2, float& numAcc, int& cnt)
{
    // ---- numerator: lane (hi,c) owns steps t0+2hi+{0,1} of batch c ----
    if (MODE != 3) {
        int m0 = hi ? pt.msk.z : pt.msk.x;
        int m1 = hi ? pt.msk.w : pt.msk.y;
        float c0;
        if (MODE == 1 && hi == 0)
            c0 = ldsS[pt.tg0] + gem0;              // t=0: start+em0, unmasked
        else
            c0 = m0 ? (ldsT[pt.tgp * NT + pt.tg0] + gem0) : 0.0f;
        float c1 = m1 ? (ldsT[pt.tg0 * NT + pt.tg1] + gem1) : 0.0f;
        numAcc += c0 + c1;
        if (hi == 0)
            cnt += (pt.msk.x ? 1 : 0) + (pt.msk.y ? 1 : 0) +
                   (pt.msk.z ? 1 : 0) + (pt.msk.w ? 1 : 0);
    }
    // ---- w recurrence: 4 steps, all in registers ----
#pragma unroll
    for (int k = 0; k < CH; ++k) {
        int mkk = (k == 0) ? pt.msk.x : (k == 1) ? pt.msk.y
                : (k == 2) ? pt.msk.z : pt.msk.w;
        if (MODE == 1 && k == 0) {
#pragma unroll
            for (int r = 0; r < 12; ++r) {
                int R = (r & 3) + 8 * (r >> 2);
                w[r] = __expf(ldsS[R + 4 * hi] + em[0][r]);
            }
            continue;
        }
        // B = bf16(W) in MFMA-B layout via cvt_pk + permlane32_swap (verified R5)
        unsigned aw = cvtpk(w[0], w[1]);
        unsigned bw = cvtpk(w[2], w[3]);
        unsigned cw = cvtpk(w[4], w[5]);
        unsigned dw = cvtpk(w[6], w[7]);
        unsigned ew = cvtpk(w[8], w[9]);
        unsigned fw = cvtpk(w[10], w[11]);
        uint2v s1 = __builtin_amdgcn_permlane32_swap(aw, cw, false, false);
        uint2v s2 = __builtin_amdgcn_permlane32_swap(bw, dw, false, false);
        uint2v s3 = __builtin_amdgcn_permlane32_swap(ew, 0u, false, false);
        uint2v s4 = __builtin_amdgcn_permlane32_swap(fw, 0u, false, false);
        union { unsigned u[4]; bf16x8 v; } B1, B2;
        B1.u[0] = s1[0]; B1.u[1] = s2[0]; B1.u[2] = s1[1]; B1.u[3] = s2[1];
        B2.u[0] = s3[0]; B2.u[1] = s4[0]; B2.u[2] = s3[1]; B2.u[3] = s4[1];
        // independent MFMAs (no serial acc dependency)
        f32x16 z16 = {};
        f32x16 acc1 = __builtin_amdgcn_mfma_f32_32x32x16_bf16(A1, B1.v, z16, 0, 0, 0);
        f32x16 acc2 = __builtin_amdgcn_mfma_f32_32x32x16_bf16(A2, B2.v, z16, 0, 0, 0);
        bool m = (mkk != 0);
#pragma unroll
        for (int r = 0; r < 12; ++r) {
            float q = (acc1[r] + acc2[r]) * __expf(em[k][r]);
            w[r] = m ? q : w[r];
        }
        if (RN && k == CH - 1) {   // every 8 steps; invariant stays exact
            float zh = ((w[0] + w[1]) + (w[2] + w[3])) +
                       ((w[4] + w[5]) + (w[6] + w[7])) +
                       ((w[8] + w[9]) + (w[10] + w[11]));
            float zt = zh + __shfl_xor(zh, 32);
            float rz = __builtin_amdgcn_rcpf(zt);
            lz2 += __log2f(zt);
#pragma unroll
            for (int r = 0; r < 12; ++r) w[r] *= rz;
        }
    }
}

// One pipeline iteration, all indices compile-time (rule #20).
// NC chunks total; WARM2: first two chunks are warmup (p>0).
template<int I, int NC, bool WARM2>
__device__ __forceinline__ void iter_fn(
    int a, const float* __restrict__ fbl, const int* __restrict__ tbl,
    const int* __restrict__ mbl,
    float (&em)[2][CH][12], PT (&pt)[3], float (&gem)[2][2],
    bf16x8 A1, bf16x8 A2,
    const float* __restrict__ ldsT, const float* __restrict__ ldsS,
    int hi, float (&w)[12], float& lz2, float& numAcc, int& cnt)
{
    const int t0 = a + 4 * I - (WARM2 ? 8 : 0);
    if (I + 2 < NC) pt_load(pt[(I + 2) % 3], tbl, mbl, t0 + 8, hi);
    if (I + 1 < NC) ldem(em[(I + 1) & 1], fbl, t0 + 4, hi);
    constexpr int FM = WARM2 ? 2 : 0;
    if (I + 1 < NC && I + 1 >= FM) {
        const PT& pn = pt[(I + 1) % 3];
        gem[(I + 1) & 1][0] = fbl[(size_t)(t0 + 4 + 2 * hi) * NT + pn.tg0];
        gem[(I + 1) & 1][1] = fbl[(size_t)(t0 + 5 + 2 * hi) * NT + pn.tg1];
    }
    constexpr int MODE = (WARM2 && I < 2) ? 3 : ((!WARM2 && I == 0) ? 1 : 0);
    run_chunk<MODE, (I & 1) != 0>(em[I & 1], pt[I % 3], gem[I & 1][0], gem[I & 1][1],
                                  A1, A2, ldsT, ldsS, hi, w, lz2, numAcc, cnt);
}

extern "C" __global__ void __launch_bounds__(64)
crf_fwd(const float* __restrict__ feat,
        const int* __restrict__ maskp, const int* __restrict__ target,
        const float* __restrict__ startT, const float* __restrict__ endT,
        const float* __restrict__ trans,
        float* __restrict__ dP, float* __restrict__ nP, int* __restrict__ cP)
{
    __shared__ float ldsT[NT * NT];
    __shared__ float ldsS[NT];
    __shared__ float ldsE[NT];

    const int tid = threadIdx.x;
    const int hi = tid >> 5;
    const int c = tid & 31;
    const int bid = blockIdx.x;       // 1024 = (bg, p)
    const int bg = bid >> 5;
    const int p = bid & (NSEG - 1);
    const int b = bg * 32 + c;

    for (int i = tid; i < NT * NT; i += 64) ldsT[i] = trans[i];
    if (tid < NT) { ldsS[tid] = startT[tid]; ldsE[tid] = endT[tid]; }
    __syncthreads();

    // A = exp(trans^T) constant frags: A[row=c][k] = exp(trans[k][c]), pad 0
    union { unsigned short s[8]; bf16x8 v; } A1u, A2u;
#pragma unroll
    for (int j = 0; j < 8; ++j) {
        int k1 = 8 * hi + j;
        float v1 = (c < NT && k1 < NT) ? __expf(ldsT[k1 * NT + c]) : 0.0f;
        A1u.s[j] = bfrnd(v1);
        int k2 = 16 + 8 * hi + j;
        float v2 = (c < NT && k2 < NT) ? __expf(ldsT[k2 * NT + c]) : 0.0f;
        A2u.s[j] = bfrnd(v2);
    }

    const float* fbl = feat + (size_t)b * SQ * NT;
    const int* tbl = target + (size_t)b * SQ;
    const int* mbl = maskp + (size_t)b * SQ;

    float w[12];
#pragma unroll
    for (int r = 0; r < 12; ++r) w[r] = 1.0f;
    float lz2 = 0.f, sub2 = 0.f, numAcc = 0.f;
    int cnt = 0;
    const int a = p * LSEG;

    float em[2][CH][12];
    PT pt[3];
    float gem[2][2];

    if (p > 0) {
        // prologue: tags 2-ahead, em 1-ahead
        pt_load(pt[0], tbl, mbl, a - 8, hi);
        pt_load(pt[1], tbl, mbl, a - 4, hi);
        ldem(em[0], fbl, a - 8, hi);
        iter_fn<0, 10, true>(a, fbl, tbl, mbl, em, pt, gem, A1u.v, A2u.v, ldsT, ldsS, hi, w, lz2, numAcc, cnt);
        iter_fn<1, 10, true>(a, fbl, tbl, mbl, em, pt, gem, A1u.v, A2u.v, ldsT, ldsS, hi, w, lz2, numAcc, cnt);
        // capture segment-start scale (state = w_{a-1}); cancels warmup init
        {
            float zh = ((w[0] + w[1]) + (w[2] + w[3])) + ((w[4] + w[5]) + (w[6] + w[7])) +
                       ((w[8] + w[9]) + (w[10] + w[11]));
            float zt = zh + __shfl_xor(zh, 32);
            sub2 = lz2 + __log2f(zt);
        }
        iter_fn<2, 10, true>(a, fbl, tbl, mbl, em, pt, gem, A1u.v, A2u.v, ldsT, ldsS, hi, w, lz2, numAcc, cnt);
        iter_fn<3, 10, true>(a, fbl, tbl, mbl, em, pt, gem, A1u.v, A2u.v, ldsT, ldsS, hi, w, lz2, numAcc, cnt);
        iter_fn<4, 10, true>(a, fbl, tbl, mbl, em, pt, gem, A1u.v, A2u.v, ldsT, ldsS, hi, w, lz2, numAcc, cnt);
        iter_fn<5, 10, true>(a, fbl, tbl, mbl, em, pt, gem, A1u.v, A2u.v, ldsT, ldsS, hi, w, lz2, numAcc, cnt);
        iter_fn<6, 10, true>(a, fbl, tbl, mbl, em, pt, gem, A1u.v, A2u.v, ldsT, ldsS, hi, w, lz2, numAcc, cnt);
        iter_fn<7, 10, true>(a, fbl, tbl, mbl, em, pt, gem, A1u.v, A2u.v, ldsT, ldsS, hi, w, lz2, numAcc, cnt);
        iter_fn<8, 10, true>(a, fbl, tbl, mbl, em, pt, gem, A1u.v, A2u.v, ldsT, ldsS, hi, w, lz2, numAcc, cnt);
        iter_fn<9, 10, true>(a, fbl, tbl, mbl, em, pt, gem, A1u.v, A2u.v, ldsT, ldsS, hi, w, lz2, numAcc, cnt);
    } else {
        pt_load(pt[0], tbl, mbl, 0, hi);
        pt_load(pt[1], tbl, mbl, 4, hi);
        ldem(em[0], fbl, 0, hi);
        gem[0][0] = fbl[(size_t)(2 * hi) * NT + pt[0].tg0];
        gem[0][1] = fbl[(size_t)(2 * hi + 1) * NT + pt[0].tg1];
        iter_fn<0, 8, false>(0, fbl, tbl, mbl, em, pt, gem, A1u.v, A2u.v, ldsT, ldsS, hi, w, lz2, numAcc, cnt);
        iter_fn<1, 8, false>(0, fbl, tbl, mbl, em, pt, gem, A1u.v, A2u.v, ldsT, ldsS, hi, w, lz2, numAcc, cnt);
        iter_fn<2, 8, false>(0, fbl, tbl, mbl, em, pt, gem, A1u.v, A2u.v, ldsT, ldsS, hi, w, lz2, numAcc, cnt);
        iter_fn<3, 8, false>(0, fbl, tbl, mbl, em, pt, gem, A1u.v, A2u.v, ldsT, ldsS, hi, w, lz2, numAcc, cnt);
        iter_fn<4, 8, false>(0, fbl, tbl, mbl, em, pt, gem, A1u.v, A2u.v, ldsT, ldsS, hi, w, lz2, numAcc, cnt);
        iter_fn<5, 8, false>(0, fbl, tbl, mbl, em, pt, gem, A1u.v, A2u.v, ldsT, ldsS, hi, w, lz2, numAcc, cnt);
        iter_fn<6, 8, false>(0, fbl, tbl, mbl, em, pt, gem, A1u.v, A2u.v, ldsT, ldsS, hi, w, lz2, numAcc, cnt);
        iter_fn<7, 8, false>(0, fbl, tbl, mbl, em, pt, gem, A1u.v, A2u.v, ldsT, ldsS, hi, w, lz2, numAcc, cnt);
    }

    // ---- segment epilogue ----
    float ze = 0.0f;
#pragma unroll
    for (int r = 0; r < 12; ++r) {
        int R = (r & 3) + 8 * (r >> 2) + 4 * hi;
        float wv = w[r];
        if (p == NSEG - 1) wv *= __expf(ldsE[R]);
        ze += wv;
    }
    float zt = ze + __shfl_xor(ze, 32);
    float res = (lz2 + __log2f(zt) - sub2) * 0.6931471805599453f;
    float ntot = numAcc + __shfl_xor(numAcc, 32);
    if (hi == 0) {
        dP[p * NB + b] = res;
        nP[p * NB + b] = ntot;
        cP[p * NB + b] = cnt;
    }
}

extern "C" __global__ void __launch_bounds__(64)
crf_combine(const float* __restrict__ dP, const float* __restrict__ nP,
            const int* __restrict__ cP, const int* __restrict__ target,
            const float* __restrict__ endT, float* __restrict__ bpart)
{
    const int b = blockIdx.x * 64 + threadIdx.x;
    float den = 0.f, num = 0.f;
    int cnt = 0;
#pragma unroll 8
    for (int p = 0; p < NSEG; ++p) {
        den += dP[p * NB + b];
        num += nP[p * NB + b];
        cnt += cP[p * NB + b];
    }
    int lastTag = target[(size_t)b * SQ + (cnt - 1)];
    float llh = (num + endT[lastTag]) - den;
#pragma unroll
    for (int m = 1; m < 64; m <<= 1) llh += __shfl_xor(llh, m, 64);
    if (threadIdx.x == 0) bpart[blockIdx.x] = llh;
}

extern "C" __global__ void __launch_bounds__(64)
crf_final(const float* __restrict__ bpart, float* __restrict__ out)
{
    float s = (threadIdx.x < NB / 64) ? bpart[threadIdx.x] : 0.0f;
#pragma unroll
    for (int m = 1; m < 64; m <<= 1) s += __shfl_xor(s, m, 64);
    if (threadIdx.x == 0) out[0] = -s * (1.0f / NB);
}

extern "C" void kernel_launch(void* const* d_in, const int* in_sizes, int n_in,
                              void* d_out, int out_size, void* d_ws, size_t ws_size,
                              hipStream_t stream)
{
    const float* feat   = (const float*)d_in[0];
    const int*   maskp  = (const int*)d_in[1];
    const int*   target = (const int*)d_in[2];
    const float* startT = (const float*)d_in[3];
    const float* endT   = (const float*)d_in[4];
    const float* trans  = (const float*)d_in[5];

    float* dP = (float*)d_ws;                    // [NSEG*NB]
    float* nP = dP + NSEG * NB;                  // [NSEG*NB]
    int*   cP = (int*)(nP + NSEG * NB);          // [NSEG*NB]
    float* bpart = (float*)(cP + NSEG * NB);     // [NB/64]

    crf_fwd<<<(NB / 32) * NSEG, 64, 0, stream>>>(feat, maskp, target, startT, endT,
                                                 trans, dP, nP, cP);
    crf_combine<<<NB / 64, 64, 0, stream>>>(dP, nP, cP, target, endT, bpart);
    crf_final<<<1, 64, 0, stream>>>(bpart, (float*)d_out);
}

// Round 15
// 38.448 us; speedup vs baseline: 1.3229x; 1.0906x over previous
//
#include <hip/hip_runtime.h>

#define NT 24
#define SQ 1024
#define NB 1024
#define NSEG 32
#define LSEG 32
#define CH 4

typedef float f32x16 __attribute__((ext_vector_type(16)));
typedef short bf16x8 __attribute__((ext_vector_type(8)));
typedef unsigned int uint2v __attribute__((ext_vector_type(2)));

__device__ __forceinline__ unsigned short bfrnd(float x) {
    unsigned u = __float_as_uint(x);
    return (unsigned short)((u + 0x7fffu + ((u >> 16) & 1u)) >> 16);
}
__device__ __forceinline__ unsigned cvtpk(float lo, float hi) {
    unsigned r;
    asm("v_cvt_pk_bf16_f32 %0, %1, %2" : "=v"(r) : "v"(lo), "v"(hi));
    return r;
}

// Tag/mask bundle for one 4-step chunk (loaded TWO chunks ahead so the
// dependent em-gather has its tag resident when issued one chunk ahead).
struct PT { int4 msk; int tg0, tg1, tgp; };

__device__ __forceinline__ void pt_load(PT& pt, const int* __restrict__ tbl,
                                        const int* __restrict__ mbl, int t0, int hi)
{
    pt.msk = *(const int4*)(mbl + t0);
    int t = t0 + 2 * hi;                       // (t0 even) -> 8B aligned
    int2 tt = *(const int2*)(tbl + t);
    pt.tg0 = tt.x & 31;
    pt.tg1 = tt.y & 31;
    pt.tgp = tbl[t > 0 ? t - 1 : 0] & 31;
}

// em chunk: 3 float4 per step per lane (lane c = batch, hi = tag-quad half).
__device__ __forceinline__ void ldem(float (&e)[CH][12],
                                     const float* __restrict__ fbl, int t0, int hi)
{
#pragma unroll
    for (int k = 0; k < CH; ++k) {
        const float* r = fbl + (size_t)(t0 + k) * NT + hi * 4;
        float4 e0 = *(const float4*)(r);
        float4 e1 = *(const float4*)(r + 8);
        float4 e2 = *(const float4*)(r + 16);
        e[k][0] = e0.x; e[k][1] = e0.y; e[k][2] = e0.z; e[k][3] = e0.w;
        e[k][4] = e1.x; e[k][5] = e1.y; e[k][6] = e1.z; e[k][7] = e1.w;
        e[k][8] = e2.x; e[k][9] = e2.y; e[k][10] = e2.z; e[k][11] = e2.w;
    }
}

// MODE: 0 normal, 1 first chunk of sequence (t=0 init), 3 warmup (no numerator).
// RN: renormalize at chunk end (every other chunk -> every 8 steps).
template<int MODE, bool RN>
__device__ __forceinline__ void run_chunk(
    const float (&em)[CH][12], const PT& pt, float gem0, float gem1,
    bf16x8 A1, bf16x8 A2,
    const float* __restrict__ ldsT, const float* __restrict__ ldsS,
    int hi, float (&w)[12], float& lz2, float& numAcc, int& cnt)
{
    // ---- numerator: lane (hi,c) owns steps t0+2hi+{0,1} of batch c ----
    if (MODE != 3) {
        int m0 = hi ? pt.msk.z : pt.msk.x;
        int m1 = hi ? pt.msk.w : pt.msk.y;
        float c0;
        if (MODE == 1 && hi == 0)
            c0 = ldsS[pt.tg0] + gem0;              // t=0: start+em0, unmasked
        else
            c0 = m0 ? (ldsT[pt.tgp * NT + pt.tg0] + gem0) : 0.0f;
        float c1 = m1 ? (ldsT[pt.tg0 * NT + pt.tg1] + gem1) : 0.0f;
        numAcc += c0 + c1;
        if (hi == 0)
            cnt += (pt.msk.x ? 1 : 0) + (pt.msk.y ? 1 : 0) +
                   (pt.msk.z ? 1 : 0) + (pt.msk.w ? 1 : 0);
    }
    // ---- w recurrence: 4 steps, all in registers ----
#pragma unroll
    for (int k = 0; k < CH; ++k) {
        int mkk = (k == 0) ? pt.msk.x : (k == 1) ? pt.msk.y
                : (k == 2) ? pt.msk.z : pt.msk.w;
        if (MODE == 1 && k == 0) {
#pragma unroll
            for (int r = 0; r < 12; ++r) {
                int R = (r & 3) + 8 * (r >> 2);
                w[r] = __expf(ldsS[R + 4 * hi] + em[0][r]);
            }
            continue;
        }
        // B = bf16(W) in MFMA-B layout via cvt_pk + permlane32_swap (verified R5)
        unsigned aw = cvtpk(w[0], w[1]);
        unsigned bw = cvtpk(w[2], w[3]);
        unsigned cw = cvtpk(w[4], w[5]);
        unsigned dw = cvtpk(w[6], w[7]);
        unsigned ew = cvtpk(w[8], w[9]);
        unsigned fw = cvtpk(w[10], w[11]);
        uint2v s1 = __builtin_amdgcn_permlane32_swap(aw, cw, false, false);
        uint2v s2 = __builtin_amdgcn_permlane32_swap(bw, dw, false, false);
        uint2v s3 = __builtin_amdgcn_permlane32_swap(ew, 0u, false, false);
        uint2v s4 = __builtin_amdgcn_permlane32_swap(fw, 0u, false, false);
        union { unsigned u[4]; bf16x8 v; } B1, B2;
        B1.u[0] = s1[0]; B1.u[1] = s2[0]; B1.u[2] = s1[1]; B1.u[3] = s2[1];
        B2.u[0] = s3[0]; B2.u[1] = s4[0]; B2.u[2] = s3[1]; B2.u[3] = s4[1];
        // independent MFMAs (no serial acc dependency)
        f32x16 z16 = {};
        f32x16 acc1 = __builtin_amdgcn_mfma_f32_32x32x16_bf16(A1, B1.v, z16, 0, 0, 0);
        f32x16 acc2 = __builtin_amdgcn_mfma_f32_32x32x16_bf16(A2, B2.v, z16, 0, 0, 0);
        bool m = (mkk != 0);
#pragma unroll
        for (int r = 0; r < 12; ++r) {
            float q = (acc1[r] + acc2[r]) * __expf(em[k][r]);
            w[r] = m ? q : w[r];
        }
        if (RN && k == CH - 1) {   // every 8 steps; invariant stays exact
            float zh = ((w[0] + w[1]) + (w[2] + w[3])) +
                       ((w[4] + w[5]) + (w[6] + w[7])) +
                       ((w[8] + w[9]) + (w[10] + w[11]));
            float zt = zh + __shfl_xor(zh, 32);
            float rz = __builtin_amdgcn_rcpf(zt);
            lz2 += __log2f(zt);
#pragma unroll
            for (int r = 0; r < 12; ++r) w[r] *= rz;
        }
    }
}

// One pipeline iteration, all indices compile-time (rule #20).
// NC chunks total; WARM = number of warmup chunks (0 or 1).
template<int I, int NC, int WARM>
__device__ __forceinline__ void iter_fn(
    int a, const float* __restrict__ fbl, const int* __restrict__ tbl,
    const int* __restrict__ mbl,
    float (&em)[2][CH][12], PT (&pt)[3], float (&gem)[2][2],
    bf16x8 A1, bf16x8 A2,
    const float* __restrict__ ldsT, const float* __restrict__ ldsS,
    int hi, float (&w)[12], float& lz2, float& numAcc, int& cnt)
{
    const int t0 = a + 4 * I - 4 * WARM;
    if (I + 2 < NC) pt_load(pt[(I + 2) % 3], tbl, mbl, t0 + 8, hi);
    if (I + 1 < NC) ldem(em[(I + 1) & 1], fbl, t0 + 4, hi);
    if (I + 1 < NC && I + 1 >= WARM) {
        const PT& pn = pt[(I + 1) % 3];
        gem[(I + 1) & 1][0] = fbl[(size_t)(t0 + 4 + 2 * hi) * NT + pn.tg0];
        gem[(I + 1) & 1][1] = fbl[(size_t)(t0 + 5 + 2 * hi) * NT + pn.tg1];
    }
    constexpr int MODE = (WARM > 0 && I < WARM) ? 3 : ((WARM == 0 && I == 0) ? 1 : 0);
    run_chunk<MODE, (I & 1) != 0>(em[I & 1], pt[I % 3], gem[I & 1][0], gem[I & 1][1],
                                  A1, A2, ldsT, ldsS, hi, w, lz2, numAcc, cnt);
}

extern "C" __global__ void __launch_bounds__(64)
crf_fwd(const float* __restrict__ feat,
        const int* __restrict__ maskp, const int* __restrict__ target,
        const float* __restrict__ startT, const float* __restrict__ endT,
        const float* __restrict__ trans,
        float* __restrict__ dP, float* __restrict__ nP, int* __restrict__ cP)
{
    __shared__ float ldsT[NT * NT];
    __shared__ float ldsS[NT];
    __shared__ float ldsE[NT];

    const int tid = threadIdx.x;
    const int hi = tid >> 5;
    const int c = tid & 31;
    const int bid = blockIdx.x;       // 1024 = (bg, p)
    const int bg = bid >> 5;
    const int p = bid & (NSEG - 1);
    const int b = bg * 32 + c;

    for (int i = tid; i < NT * NT; i += 64) ldsT[i] = trans[i];
    if (tid < NT) { ldsS[tid] = startT[tid]; ldsE[tid] = endT[tid]; }
    __syncthreads();

    // A = exp(trans^T) constant frags: A[row=c][k] = exp(trans[k][c]), pad 0
    union { unsigned short s[8]; bf16x8 v; } A1u, A2u;
#pragma unroll
    for (int j = 0; j < 8; ++j) {
        int k1 = 8 * hi + j;
        float v1 = (c < NT && k1 < NT) ? __expf(ldsT[k1 * NT + c]) : 0.0f;
        A1u.s[j] = bfrnd(v1);
        int k2 = 16 + 8 * hi + j;
        float v2 = (c < NT && k2 < NT) ? __expf(ldsT[k2 * NT + c]) : 0.0f;
        A2u.s[j] = bfrnd(v2);
    }

    const float* fbl = feat + (size_t)b * SQ * NT;
    const int* tbl = target + (size_t)b * SQ;
    const int* mbl = maskp + (size_t)b * SQ;

    float w[12];
#pragma unroll
    for (int r = 0; r < 12; ++r) w[r] = 1.0f;
    float lz2 = 0.f, sub2 = 0.f, numAcc = 0.f;
    int cnt = 0;
    const int a = p * LSEG;

    float em[2][CH][12];
    PT pt[3];
    float gem[2][2];

    if (p > 0) {
        // prologue: tags 2-ahead, em 1-ahead; 4-step warmup (1 chunk).
        // Birkhoff contraction ~0.1/step: direction error 0.4*1e-4 by segment
        // start -> ~1e-3 per llh, far under threshold.
        pt_load(pt[0], tbl, mbl, a - 4, hi);
        pt_load(pt[1], tbl, mbl, a, hi);
        ldem(em[0], fbl, a - 4, hi);
        iter_fn<0, 9, 1>(a, fbl, tbl, mbl, em, pt, gem, A1u.v, A2u.v, ldsT, ldsS, hi, w, lz2, numAcc, cnt);
        // capture segment-start scale (state = w_{a-1}); cancels warmup init
        {
            float zh = ((w[0] + w[1]) + (w[2] + w[3])) + ((w[4] + w[5]) + (w[6] + w[7])) +
                       ((w[8] + w[9]) + (w[10] + w[11]));
            float zt = zh + __shfl_xor(zh, 32);
            sub2 = lz2 + __log2f(zt);
        }
        iter_fn<1, 9, 1>(a, fbl, tbl, mbl, em, pt, gem, A1u.v, A2u.v, ldsT, ldsS, hi, w, lz2, numAcc, cnt);
        iter_fn<2, 9, 1>(a, fbl, tbl, mbl, em, pt, gem, A1u.v, A2u.v, ldsT, ldsS, hi, w, lz2, numAcc, cnt);
        iter_fn<3, 9, 1>(a, fbl, tbl, mbl, em, pt, gem, A1u.v, A2u.v, ldsT, ldsS, hi, w, lz2, numAcc, cnt);
        iter_fn<4, 9, 1>(a, fbl, tbl, mbl, em, pt, gem, A1u.v, A2u.v, ldsT, ldsS, hi, w, lz2, numAcc, cnt);
        iter_fn<5, 9, 1>(a, fbl, tbl, mbl, em, pt, gem, A1u.v, A2u.v, ldsT, ldsS, hi, w, lz2, numAcc, cnt);
        iter_fn<6, 9, 1>(a, fbl, tbl, mbl, em, pt, gem, A1u.v, A2u.v, ldsT, ldsS, hi, w, lz2, numAcc, cnt);
        iter_fn<7, 9, 1>(a, fbl, tbl, mbl, em, pt, gem, A1u.v, A2u.v, ldsT, ldsS, hi, w, lz2, numAcc, cnt);
        iter_fn<8, 9, 1>(a, fbl, tbl, mbl, em, pt, gem, A1u.v, A2u.v, ldsT, ldsS, hi, w, lz2, numAcc, cnt);
    } else {
        pt_load(pt[0], tbl, mbl, 0, hi);
        pt_load(pt[1], tbl, mbl, 4, hi);
        ldem(em[0], fbl, 0, hi);
        gem[0][0] = fbl[(size_t)(2 * hi) * NT + pt[0].tg0];
        gem[0][1] = fbl[(size_t)(2 * hi + 1) * NT + pt[0].tg1];
        iter_fn<0, 8, 0>(0, fbl, tbl, mbl, em, pt, gem, A1u.v, A2u.v, ldsT, ldsS, hi, w, lz2, numAcc, cnt);
        iter_fn<1, 8, 0>(0, fbl, tbl, mbl, em, pt, gem, A1u.v, A2u.v, ldsT, ldsS, hi, w, lz2, numAcc, cnt);
        iter_fn<2, 8, 0>(0, fbl, tbl, mbl, em, pt, gem, A1u.v, A2u.v, ldsT, ldsS, hi, w, lz2, numAcc, cnt);
        iter_fn<3, 8, 0>(0, fbl, tbl, mbl, em, pt, gem, A1u.v, A2u.v, ldsT, ldsS, hi, w, lz2, numAcc, cnt);
        iter_fn<4, 8, 0>(0, fbl, tbl, mbl, em, pt, gem, A1u.v, A2u.v, ldsT, ldsS, hi, w, lz2, numAcc, cnt);
        iter_fn<5, 8, 0>(0, fbl, tbl, mbl, em, pt, gem, A1u.v, A2u.v, ldsT, ldsS, hi, w, lz2, numAcc, cnt);
        iter_fn<6, 8, 0>(0, fbl, tbl, mbl, em, pt, gem, A1u.v, A2u.v, ldsT, ldsS, hi, w, lz2, numAcc, cnt);
        iter_fn<7, 8, 0>(0, fbl, tbl, mbl, em, pt, gem, A1u.v, A2u.v, ldsT, ldsS, hi, w, lz2, numAcc, cnt);
    }

    // ---- segment epilogue ----
    float ze = 0.0f;
#pragma unroll
    for (int r = 0; r < 12; ++r) {
        int R = (r & 3) + 8 * (r >> 2) + 4 * hi;
        float wv = w[r];
        if (p == NSEG - 1) wv *= __expf(ldsE[R]);
        ze += wv;
    }
    float zt = ze + __shfl_xor(ze, 32);
    float res = (lz2 + __log2f(zt) - sub2) * 0.6931471805599453f;
    float ntot = numAcc + __shfl_xor(numAcc, 32);
    if (hi == 0) {
        dP[p * NB + b] = res;
        nP[p * NB + b] = ntot;
        cP[p * NB + b] = cnt;
    }
}

extern "C" __global__ void __launch_bounds__(64)
crf_combine(const float* __restrict__ dP, const float* __restrict__ nP,
            const int* __restrict__ cP, const int* __restrict__ target,
            const float* __restrict__ endT, float* __restrict__ bpart)
{
    const int b = blockIdx.x * 64 + threadIdx.x;
    float den = 0.f, num = 0.f;
    int cnt = 0;
#pragma unroll 8
    for (int p = 0; p < NSEG; ++p) {
        den += dP[p * NB + b];
        num += nP[p * NB + b];
        cnt += cP[p * NB + b];
    }
    int lastTag = target[(size_t)b * SQ + (cnt - 1)];
    float llh = (num + endT[lastTag]) - den;
#pragma unroll
    for (int m = 1; m < 64; m <<= 1) llh += __shfl_xor(llh, m, 64);
    if (threadIdx.x == 0) bpart[blockIdx.x] = llh;
}

extern "C" __global__ void __launch_bounds__(64)
crf_final(const float* __restrict__ bpart, float* __restrict__ out)
{
    float s = (threadIdx.x < NB / 64) ? bpart[threadIdx.x] : 0.0f;
#pragma unroll
    for (int m = 1; m < 64; m <<= 1) s += __shfl_xor(s, m, 64);
    if (threadIdx.x == 0) out[0] = -s * (1.0f / NB);
}

extern "C" void kernel_launch(void* const* d_in, const int* in_sizes, int n_in,
                              void* d_out, int out_size, void* d_ws, size_t ws_size,
                              hipStream_t stream)
{
    const float* feat   = (const float*)d_in[0];
    const int*   maskp  = (const int*)d_in[1];
    const int*   target = (const int*)d_in[2];
    const float* startT = (const float*)d_in[3];
    const float* endT   = (const float*)d_in[4];
    const float* trans  = (const float*)d_in[5];

    float* dP = (float*)d_ws;                    // [NSEG*NB]
    float* nP = dP + NSEG * NB;                  // [NSEG*NB]
    int*   cP = (int*)(nP + NSEG * NB);          // [NSEG*NB]
    float* bpart = (float*)(cP + NSEG * NB);     // [NB/64]

    crf_fwd<<<(NB / 32) * NSEG, 64, 0, stream>>>(feat, maskp, target, startT, endT,
                                                 trans, dP, nP, cP);
    crf_combine<<<NB / 64, 64, 0, stream>>>(dP, nP, cP, target, endT, bpart);
    crf_final<<<1, 64, 0, stream>>>(bpart, (float*)d_out);
}